// Round 2
// baseline (1003.885 us; speedup 1.0000x reference)
//
#include <hip/hip_runtime.h>
#include <hip/hip_bf16.h>

#define D 64
#define MARGIN 4e-5f

// ---------------------------------------------------------------------------
// VectorQuantizer. The harness reference is a numpy-float32 recompute, so the
// argmin must bit-match numpy f32 semantics:
//   xx  = np.sum(x**2,axis=1): pairwise 8-accumulator block (n=64)
//   dot = sgemm: sequential-k FMA chain per element
//   dist= fl32( fl32(xx+ee) - fl32(2*dot) ), np.argmin = first min
// Fast path: high-precision fp32 screen (proxy = ee - 2*dot, error ~5e-8 at
// 0.009 scale). np-f32 noise vs proxy <= ~1.6e-5, so proxy gap >= 4e-5 =>
// np argmin == proxy argmin. Ambiguous rows (~1-2%) -> exact np-f32 emulation.
// d_out (float): quantized[N*D] | loss[1] | indices[N] | perplexity[1]
// ws: counts u32[K] | nunc u32 + pad | loss f64 | ee_np f32[K] | list u32[]
// ---------------------------------------------------------------------------

__device__ __forceinline__ float np_pairwise_sumsq64(const float* a) {
    // numpy pairwise_sum, n=64, elements are fl32(a[i]*a[i])
    float r[8];
#pragma unroll
    for (int j = 0; j < 8; ++j) r[j] = __fmul_rn(a[j], a[j]);
#pragma unroll
    for (int i = 8; i < 64; i += 8)
#pragma unroll
        for (int j = 0; j < 8; ++j)
            r[j] = __fadd_rn(r[j], __fmul_rn(a[i + j], a[i + j]));
    return __fadd_rn(
        __fadd_rn(__fadd_rn(r[0], r[1]), __fadd_rn(r[2], r[3])),
        __fadd_rn(__fadd_rn(r[4], r[5]), __fadd_rn(r[6], r[7])));
}

__global__ __launch_bounds__(256) void vq_prep(const float* __restrict__ emb, int K,
                                               float* __restrict__ eenp) {
    int k = blockIdx.x * blockDim.x + threadIdx.x;
    if (k >= K) return;
    eenp[k] = np_pairwise_sumsq64(emb + (size_t)k * D);
}

// exact numpy-f32 argmin for one row, per-thread sequential (overflow only)
__device__ int np_exact_argmin(const float* xr, float xx,
                               const float* __restrict__ emb,
                               const float* __restrict__ eenp, int K) {
    float bm = 1e30f;
    int bi = 0;
    for (int k = 0; k < K; ++k) {
        const float* e = emb + (size_t)k * D;
        float dot = 0.f;
#pragma unroll 8
        for (int d = 0; d < D; ++d) dot = __fmaf_rn(xr[d], e[d], dot);
        float dist = __fsub_rn(__fadd_rn(xx, eenp[k]), __fmul_rn(2.0f, dot));
        if (dist < bm) { bm = dist; bi = k; }
    }
    return bi;
}

__global__ __launch_bounds__(256) void vq_screen(
    const float* __restrict__ x, const float* __restrict__ emb,
    const float* __restrict__ eenp, int N, int K,
    float* __restrict__ outq, float* __restrict__ outidx,
    unsigned* __restrict__ counts, double* __restrict__ loss,
    unsigned* __restrict__ nunc, unsigned* __restrict__ list, unsigned cap) {
    int r = blockIdx.x * 256 + threadIdx.x;
    double lpart = 0.0;
    if (r < N) {
        float xr[D];
        const float4* xp = (const float4*)(x + (size_t)r * D);
#pragma unroll
        for (int j = 0; j < D / 4; ++j) {
            float4 v = xp[j];
            xr[4 * j + 0] = v.x; xr[4 * j + 1] = v.y;
            xr[4 * j + 2] = v.z; xr[4 * j + 3] = v.w;
        }
        float m1 = 1e30f, m2 = 1e30f;
        int bi = 0;
        for (int k = 0; k < K; ++k) {
            const float4* ep = (const float4*)(emb + (size_t)k * D);  // uniform
            float a0 = 0.f, a1 = 0.f, a2 = 0.f, a3 = 0.f;
#pragma unroll
            for (int j = 0; j < D / 4; ++j) {
                float4 ev = ep[j];
                a0 = fmaf(xr[4 * j + 0], ev.x, a0);
                a1 = fmaf(xr[4 * j + 1], ev.y, a1);
                a2 = fmaf(xr[4 * j + 2], ev.z, a2);
                a3 = fmaf(xr[4 * j + 3], ev.w, a3);
            }
            float dot = (a0 + a1) + (a2 + a3);
            float dist = fmaf(-2.f, dot, eenp[k]);  // proxy: no xx offset
            if (dist < m1) { m2 = m1; m1 = dist; bi = k; }
            else if (dist < m2) { m2 = dist; }
        }
        bool decided = (m2 - m1 >= MARGIN);
        if (!decided) {
            unsigned pos = atomicAdd(nunc, 1u);
            if (pos < cap) {
                list[pos] = r;
            } else {  // overflow: exact np emulation inline
                float xx = np_pairwise_sumsq64(xr);
                bi = np_exact_argmin(xr, xx, emb, eenp, K);
                decided = true;
            }
        }
        if (decided) {
            outidx[r] = (float)bi;
            const float4* bp = (const float4*)(emb + (size_t)bi * D);
            float4* qp = (float4*)(outq + (size_t)r * D);
#pragma unroll
            for (int j = 0; j < D / 4; ++j) {
                float4 ev = bp[j];
                qp[j] = ev;
                double d0 = (double)ev.x - (double)xr[4 * j + 0];
                double d1 = (double)ev.y - (double)xr[4 * j + 1];
                double d2 = (double)ev.z - (double)xr[4 * j + 2];
                double d3 = (double)ev.w - (double)xr[4 * j + 3];
                lpart += d0 * d0 + d1 * d1 + d2 * d2 + d3 * d3;
            }
            atomicAdd(counts + bi, 1u);
        }
    }
#pragma unroll
    for (int off = 32; off; off >>= 1) lpart += __shfl_down(lpart, off);
    __shared__ double ls[4];
    if ((threadIdx.x & 63) == 0) ls[threadIdx.x >> 6] = lpart;
    __syncthreads();
    if (threadIdx.x == 0) {
        double s = ls[0] + ls[1] + ls[2] + ls[3];
        atomicAdd(loss, s);
    }
}

// wave-per-row exact numpy-f32 argmin for ambiguous rows
__global__ __launch_bounds__(64) void vq_fallback(
    const float* __restrict__ x, const float* __restrict__ emb,
    const float* __restrict__ eenp, int N, int K,
    float* __restrict__ outq, float* __restrict__ outidx,
    unsigned* __restrict__ counts, double* __restrict__ loss,
    const unsigned* __restrict__ nunc, const unsigned* __restrict__ list,
    unsigned cap) {
    unsigned n = *nunc;
    if (n > cap) n = cap;
    int lane = threadIdx.x;
    int KP = K / 64;  // 16
    __shared__ float sx[D];
    for (unsigned i = blockIdx.x; i < n; i += gridDim.x) {
        int r = (int)list[i];
        sx[lane] = x[(size_t)r * D + lane];
        __syncthreads();
        // every lane computes numpy-exact xx redundantly (broadcast LDS reads)
        float xx = np_pairwise_sumsq64(sx);
        float bm = 1e30f;
        int bi = 0;
#pragma unroll 4
        for (int kk = 0; kk < KP; ++kk) {
            int k = lane * KP + kk;  // ascending within lane
            const float* e = emb + (size_t)k * D;
            float dot = 0.f;
#pragma unroll 8
            for (int d = 0; d < D; ++d) dot = __fmaf_rn(sx[d], e[d], dot);
            float dist = __fsub_rn(__fadd_rn(xx, eenp[k]), __fmul_rn(2.0f, dot));
            if (dist < bm) { bm = dist; bi = k; }
        }
        // wave argmin, ties -> lowest index (numpy first-occurrence)
#pragma unroll
        for (int off = 1; off < 64; off <<= 1) {
            float ov = __shfl_xor(bm, off);
            int oi = __shfl_xor(bi, off);
            if (ov < bm || (ov == bm && oi < bi)) { bm = ov; bi = oi; }
        }
        float ev = emb[(size_t)bi * D + lane];
        float xv = sx[lane];
        outq[(size_t)r * D + lane] = ev;
        double df = (double)ev - (double)xv;
        double lp = df * df;
#pragma unroll
        for (int off = 32; off; off >>= 1) lp += __shfl_down(lp, off);
        if (lane == 0) {
            outidx[r] = (float)bi;
            atomicAdd(counts + bi, 1u);
            atomicAdd(loss, lp);
        }
        __syncthreads();
    }
}

__global__ __launch_bounds__(256) void vq_final(
    const unsigned* __restrict__ counts, const double* __restrict__ loss,
    int N, int K, float* __restrict__ out_loss, float* __restrict__ out_perp) {
    double part = 0.0;
    for (int k = threadIdx.x; k < K; k += 256) {
        double p = (double)counts[k] / (double)N;
        part += p * log(p + 1e-10);
    }
#pragma unroll
    for (int off = 32; off; off >>= 1) part += __shfl_down(part, off);
    __shared__ double ls[4];
    if ((threadIdx.x & 63) == 0) ls[threadIdx.x >> 6] = part;
    __syncthreads();
    if (threadIdx.x == 0) {
        double s = ls[0] + ls[1] + ls[2] + ls[3];
        *out_perp = (float)exp(-s);
        double diff2 = *loss / ((double)N * (double)D);
        *out_loss = (float)(1.25 * diff2);
    }
}

extern "C" void kernel_launch(void* const* d_in, const int* in_sizes, int n_in,
                              void* d_out, int out_size, void* d_ws, size_t ws_size,
                              hipStream_t stream) {
    const float* x = (const float*)d_in[0];
    const float* emb = (const float*)d_in[1];
    int N = in_sizes[0] / D;
    int K = in_sizes[1] / D;

    float* outq = (float*)d_out;
    float* out_loss = outq + (size_t)N * D;
    float* outidx = out_loss + 1;
    float* out_perp = outidx + N;

    char* ws = (char*)d_ws;
    unsigned* counts = (unsigned*)ws;                        // K*4
    unsigned* nunc = (unsigned*)(ws + (size_t)K * 4);        // 4 (+4 pad)
    double* loss = (double*)(ws + (size_t)K * 4 + 8);        // 8
    float* eenp = (float*)(ws + (size_t)K * 4 + 16);         // K*4
    size_t head = (size_t)K * 8 + 16;
    unsigned* list = (unsigned*)(ws + head);
    unsigned cap = 0;
    if (ws_size > head + 4) cap = (unsigned)((ws_size - head) / 4);
    if (cap > (unsigned)N) cap = (unsigned)N;

    hipMemsetAsync(d_ws, 0, (size_t)K * 4 + 16, stream);  // counts+nunc+loss

    vq_prep<<<(K + 255) / 256, 256, 0, stream>>>(emb, K, eenp);
    vq_screen<<<(N + 255) / 256, 256, 0, stream>>>(x, emb, eenp, N, K,
                                                   outq, outidx, counts, loss,
                                                   nunc, list, cap);
    vq_fallback<<<2048, 64, 0, stream>>>(x, emb, eenp, N, K, outq, outidx,
                                         counts, loss, nunc, list, cap);
    vq_final<<<1, 256, 0, stream>>>(counts, loss, N, K, out_loss, out_perp);
}